// Round 17
// baseline (84.110 us; speedup 1.0000x reference)
//
#include <hip/hip_runtime.h>
#include <math.h>
#include <stdint.h>

// NoisyTopKGating: B=4, S=4096, D=2048, E=64, K=2
#define D_ 2048
#define E_ 64
#define T_ 16384

#define BM 64                 // tokens per block
#define BK 64                 // k per tile (4 ks-steps of 16)
#define NT 32                 // D_/BK tiles
#define ABUF_B 16384          // A: 2 planes x 2 mf x 4 ks x 1KB
#define BBUF_B 32768          // B: 2 planes x 4 frag x 4 ks x 1KB
#define BUF_B (ABUF_B + BBUF_B)   // 48 KB per buffer
#define CT_STRIDE 132         // fp32 C tile stride (epilogue)

typedef _Float16 h8 __attribute__((ext_vector_type(8)));    // 8 f16 (4 VGPR)
typedef float f16v __attribute__((ext_vector_type(16)));    // 32x32 MFMA acc

// in-register 2-plane f16 split: x = h + m/1024 (m scaled into normal range)
__device__ __forceinline__ void split2(const float4& a, const float4& b,
                                       h8& h, h8& m) {
    const float xe[8] = {a.x, a.y, a.z, a.w, b.x, b.y, b.z, b.w};
#pragma unroll
    for (int i = 0; i < 8; ++i) {
        const _Float16 hh_ = (_Float16)xe[i];              // v_cvt_f16_f32 (RNE)
        const float r = (xe[i] - (float)hh_) * 1024.0f;
        h[i] = hh_;
        m[i] = (_Float16)r;
    }
}

// async global->LDS DMA, 16 B per lane (dest = wave-uniform base + lane*16)
__device__ __forceinline__ void gload16(const void* g, void* l) {
    __builtin_amdgcn_global_load_lds(
        (const __attribute__((address_space(1))) uint32_t*)g,
        (__attribute__((address_space(3))) uint32_t*)l, 16, 0, 0);
}

// non-temporal float4 load (keep streaming x from evicting B in L2)
__device__ __forceinline__ float4 nt_load4(const float* p) {
    float4 r;
    r.x = __builtin_nontemporal_load(p + 0);
    r.y = __builtin_nontemporal_load(p + 1);
    r.z = __builtin_nontemporal_load(p + 2);
    r.w = __builtin_nontemporal_load(p + 3);
    return r;
}

// ================= per-token noisy top-2 epilogue (shared) ==================
__device__ __forceinline__ void topk_epilogue(float g, float nl, float nz,
                                              int lane, size_t tg,
                                              float* __restrict__ out_probs,
                                              float* __restrict__ out_idx) {
    // softplus(z) = max(z,0) + log1p(exp(-|z|))
    const float sp = fmaxf(nl, 0.f) + log1pf(expf(-fabsf(nl)));
    const float noisy = g + nz * sp;

    float v = noisy;
    int idx = lane;
#pragma unroll
    for (int off = 32; off > 0; off >>= 1) {
        const float ov = __shfl_xor(v, off);
        const int oi = __shfl_xor(idx, off);
        if (ov > v || (ov == v && oi < idx)) { v = ov; idx = oi; }
    }
    const float v1 = v;
    const int i1 = idx;
    v = (lane == i1) ? -INFINITY : noisy;
    idx = lane;
#pragma unroll
    for (int off = 32; off > 0; off >>= 1) {
        const float ov = __shfl_xor(v, off);
        const int oi = __shfl_xor(idx, off);
        if (ov > v || (ov == v && oi < idx)) { v = ov; idx = oi; }
    }
    const float v2 = v;
    const int i2 = idx;

    const float e2 = expf(v2 - v1);
    const float denom = 1.f + e2;
    const float p = (lane == i1) ? (1.f / denom)
                                 : ((lane == i2) ? (e2 / denom) : 0.f);
    out_probs[tg * E_ + lane] = p;
    if (lane == 0) {
        out_idx[tg * 2 + 0] = (float)i1;
        out_idx[tg * 2 + 1] = (float)i2;
    }
}

// ---------------- kernel 1: pre-split W into 2 f16 planes (32-col frags) ----
// Layout: plane p (mid x1024), frag f(4: 32 cols), ks-step s(128: 16 k),
// lane(64) -> h8.  n = f*32 + (lane&31), k = s*16 + (lane>>5)*8 + i.
__global__ void w_split_kernel(const float* __restrict__ Wg,
                               const float* __restrict__ Wn,
                               h8* __restrict__ wsp) {
    const int idx = blockIdx.x * blockDim.x + threadIdx.x;  // 0..32767
    const int lane = idx & 63;
    const int s = (idx >> 6) & 127;
    const int f = idx >> 13;
    const int n = f * 32 + (lane & 31);
    const int k0 = s * 16 + ((lane >> 5) << 3);
    const float* src = (n < 64) ? &Wg[(size_t)n * D_ + k0]
                                : &Wn[(size_t)(n - 64) * D_ + k0];
    h8 hv, mv;
#pragma unroll
    for (int i = 0; i < 8; ++i) {
        const float w = src[i];
        const _Float16 wh = (_Float16)w;
        const float r = (w - (float)wh) * 1024.0f;
        hv[i] = wh;
        mv[i] = (_Float16)r;
    }
    wsp[0 * 32768 + idx] = hv;
    wsp[1 * 32768 + idx] = mv;
}

// ---------------- kernel 2: 32x32x16 split-f16 MFMA GEMM + noisy top-2 -----
// BM=64, BK=64, grid=256 (1 block/CU). 512 threads = 8 waves = mh(2) x wn(4);
// each wave computes one full 32x32 output frag over all k (no partials).
// A reg-staged (nt-load + split + write-late); B DMA'd via global_load_lds.
// 96 KB double-buffered LDS, 1 barrier/tile.
// 3 scaled products: logit = (ah*bh) + (ah*bm + am*bh)/2^10.
__launch_bounds__(512)
__global__ void gemm_topk_kernel(const float* __restrict__ x,
                                 const h8* __restrict__ wsp,
                                 const float* __restrict__ bg,
                                 const float* __restrict__ bn,
                                 const float* __restrict__ noise,
                                 float* __restrict__ out_probs,
                                 float* __restrict__ out_idx) {
    __shared__ __align__(16) char smem[2 * BUF_B];  // 98304 B
    const int tid = threadIdx.x;
    const int lane = tid & 63;
    const int wv = tid >> 6;           // 0..7
    const int mh = wv >> 2;            // 0..1: which 32-row m-frag
    const int wn = wv & 3;             // 0..3: which 32-col n-frag
    const int block_m0 = blockIdx.x * BM;
    const char* wb = (const char*)wsp;

    // A staging ownership: thread -> (smf, sks, sl); 2 x 4 x 64 = 512
    const int smf = tid >> 8;          // m-frag 0..1
    const int sks = (tid >> 6) & 3;    // ks-step 0..3
    const int sl = tid & 63;
    const int srow = smf * 32 + (sl & 31);
    const float* asrc = x + (size_t)(block_m0 + srow) * D_
                          + sks * 16 + ((sl >> 5) << 3);
    const int aw_hi = (0 * 8 + smf * 4 + sks) * 1024 + sl * 16;
    const int aw_mid = (1 * 8 + smf * 4 + sks) * 1024 + sl * 16;

    f16v hh = {}, cx = {};             // two scaled acc chains (32 VGPR)

    // B staging: 32 rows of 1KB; rid = p*16 + f*4 + ks; 4 per wave
    auto STAGE_B = [&](int t, int b) {
        char* Bb = smem + b * BUF_B + ABUF_B;
#pragma unroll
        for (int j = 0; j < 4; ++j) {
            const int rid = wv * 4 + j;
            const int p = rid >> 4, f = (rid & 15) >> 2, ks = rid & 3;
            gload16(wb + ((size_t)(p * 32768 + f * 8192 + (t * 4 + ks) * 64 + lane)) * 16,
                    Bb + rid * 1024 + lane * 16);
        }
    };
    auto ALOAD = [&](int t, float4& ra, float4& rb) {
        ra = nt_load4(asrc + t * BK);
        rb = nt_load4(asrc + t * BK + 4);
    };
    auto ASPLIT = [&](const float4& ra, const float4& rb, int b) {
        h8 hv, mv;
        split2(ra, rb, hv, mv);
        char* Ab = smem + b * BUF_B;
        *(h8*)(Ab + aw_hi) = hv;
        *(h8*)(Ab + aw_mid) = mv;
    };
    auto COMPUTE = [&](int b) {
        const char* Ab = smem + b * BUF_B;
        const char* Bb = Ab + ABUF_B;
#pragma unroll
        for (int ks = 0; ks < 4; ++ks) {
            const h8 ah = *(const h8*)(Ab + (0 * 8 + mh * 4 + ks) * 1024 + lane * 16);
            const h8 am = *(const h8*)(Ab + (1 * 8 + mh * 4 + ks) * 1024 + lane * 16);
            const h8 bh = *(const h8*)(Bb + (0 * 16 + wn * 4 + ks) * 1024 + lane * 16);
            const h8 bm = *(const h8*)(Bb + (1 * 16 + wn * 4 + ks) * 1024 + lane * 16);
            hh = __builtin_amdgcn_mfma_f32_32x32x16_f16(ah, bh, hh, 0, 0, 0);
            cx = __builtin_amdgcn_mfma_f32_32x32x16_f16(ah, bm, cx, 0, 0, 0);
            cx = __builtin_amdgcn_mfma_f32_32x32x16_f16(am, bh, cx, 0, 0, 0);
        }
    };

    // ---- prologue ----
    float4 ra0, rb0, ra1, rb1;
    ALOAD(0, ra0, rb0);
    STAGE_B(0, 0);
    ASPLIT(ra0, rb0, 0);      // buf0 <- A(0)
    ALOAD(1, ra0, rb0);       // regs <- x(1)
    __syncthreads();

    // ---- main loop: 2 tiles per iteration (static register sets) ----
#pragma unroll 1
    for (int i = 0; i < NT / 2; ++i) {
        const int t = 2 * i;
        // tile t (buf0)
        STAGE_B(t + 1, 1);
        if (t + 2 < NT) ALOAD(t + 2, ra1, rb1);
        COMPUTE(0);
        ASPLIT(ra0, rb0, 1);
        __syncthreads();
        // tile t+1 (buf1)
        if (t + 2 < NT) STAGE_B(t + 2, 0);
        if (t + 3 < NT) ALOAD(t + 3, ra0, rb0);
        COMPUTE(1);
        if (t + 2 < NT) ASPLIT(ra1, rb1, 0);
        __syncthreads();
    }

    // ---- epilogue: combine scaled acc chains, C to LDS, noisy top-2 ----
    float* Ct = (float*)smem;  // [64][CT_STRIDE] = 33792 B
    {
        const float S1 = 1.0f / 1024.0f;
        const int col = wn * 32 + (lane & 31);
        const int rbase = 4 * (lane >> 5);
#pragma unroll
        for (int r = 0; r < 16; ++r) {
            const int row = mh * 32 + (r & 3) + 8 * (r >> 2) + rbase;
            Ct[row * CT_STRIDE + col] = hh[r] + cx[r] * S1;
        }
    }
    __syncthreads();

    const float my_bg = bg[lane];
    const float my_bn = bn[lane];
#pragma unroll 1
    for (int tt = 0; tt < 8; ++tt) {
        const int tl = wv * 8 + tt;
        const size_t tg = (size_t)block_m0 + tl;
        const float g = Ct[tl * CT_STRIDE + lane] + my_bg;
        const float nl = Ct[tl * CT_STRIDE + 64 + lane] + my_bn;
        const float nz = noise[tg * E_ + lane];
        topk_epilogue(g, nl, nz, lane, tg, out_probs, out_idx);
    }
}

// ---------------- fallback: pure-f32 fused kernel (no ws) -------------------
#define FBM 64
#define FBK 32
#define XS_STRIDE 68
#define WS_STRIDE 132
#define FCT_STRIDE 132

__launch_bounds__(256)
__global__ void noisy_topk_f32_kernel(const float* __restrict__ x,
                                      const float* __restrict__ Wg,
                                      const float* __restrict__ bg,
                                      const float* __restrict__ Wn,
                                      const float* __restrict__ bn,
                                      const float* __restrict__ noise,
                                      float* __restrict__ out_probs,
                                      float* __restrict__ out_idx) {
    __shared__ float smem[FBM * FCT_STRIDE];
    float* Xs = smem;
    float* Ws = smem + FBK * XS_STRIDE;

    const int tid = threadIdx.x;
    const int block_m0 = blockIdx.x * FBM;
    const int n0 = (tid & 31) * 4;
    const int m0 = (tid >> 5) * 8;

    float acc[8][4];
#pragma unroll
    for (int i = 0; i < 8; ++i)
#pragma unroll
        for (int j = 0; j < 4; ++j) acc[i][j] = 0.f;

    const int sj = tid & 7;
    const int sr = tid >> 3;

    for (int k0 = 0; k0 < D_; k0 += FBK) {
        __syncthreads();
#pragma unroll
        for (int it = 0; it < 2; ++it) {
            const int m = sr + it * 32;
            const float4 v = *reinterpret_cast<const float4*>(
                &x[(size_t)(block_m0 + m) * D_ + k0 + 4 * sj]);
            Xs[(4 * sj + 0) * XS_STRIDE + m] = v.x;
            Xs[(4 * sj + 1) * XS_STRIDE + m] = v.y;
            Xs[(4 * sj + 2) * XS_STRIDE + m] = v.z;
            Xs[(4 * sj + 3) * XS_STRIDE + m] = v.w;
        }
#pragma unroll
        for (int it = 0; it < 4; ++it) {
            const int n = sr + it * 32;
            const float* wrow = (n < 64) ? &Wg[(size_t)n * D_] : &Wn[(size_t)(n - 64) * D_];
            const float4 v = *reinterpret_cast<const float4*>(&wrow[k0 + 4 * sj]);
            Ws[(4 * sj + 0) * WS_STRIDE + n] = v.x;
            Ws[(4 * sj + 1) * WS_STRIDE + n] = v.y;
            Ws[(4 * sj + 2) * WS_STRIDE + n] = v.z;
            Ws[(4 * sj + 3) * WS_STRIDE + n] = v.w;
        }
        __syncthreads();
#pragma unroll
        for (int k = 0; k < FBK; ++k) {
            const float4 a0 = *reinterpret_cast<const float4*>(&Xs[k * XS_STRIDE + m0]);
            const float4 a1 = *reinterpret_cast<const float4*>(&Xs[k * XS_STRIDE + m0 + 4]);
            const float4 b4 = *reinterpret_cast<const float4*>(&Ws[k * WS_STRIDE + n0]);
            const float am[8] = {a0.x, a0.y, a0.z, a0.w, a1.x, a1.y, a1.z, a1.w};
            const float bb[4] = {b4.x, b4.y, b4.z, b4.w};
#pragma unroll
            for (int i = 0; i < 8; ++i)
#pragma unroll
                for (int j = 0; j < 4; ++j)
                    acc[i][j] = fmaf(am[i], bb[j], acc[i][j]);
        }
    }

    __syncthreads();
    float* Ct = smem;
#pragma unroll
    for (int i = 0; i < 8; ++i)
#pragma unroll
        for (int j = 0; j < 4; ++j)
            Ct[(m0 + i) * FCT_STRIDE + n0 + j] = acc[i][j];
    __syncthreads();

    const int wave = tid >> 6;
    const int lane = tid & 63;
    const float my_bg = bg[lane];
    const float my_bn = bn[lane];
#pragma unroll 1
    for (int tt = 0; tt < 16; ++tt) {
        const int tl = wave * 16 + tt;
        const size_t tg = (size_t)block_m0 + tl;
        const float g = Ct[tl * FCT_STRIDE + lane] + my_bg;
        const float nl = Ct[tl * FCT_STRIDE + 64 + lane] + my_bn;
        const float nz = noise[tg * E_ + lane];
        topk_epilogue(g, nl, nz, lane, tg, out_probs, out_idx);
    }
}

extern "C" void kernel_launch(void* const* d_in, const int* in_sizes, int n_in,
                              void* d_out, int out_size, void* d_ws, size_t ws_size,
                              hipStream_t stream) {
    const float* x = (const float*)d_in[0];
    const float* Wg = (const float*)d_in[1];
    const float* bg = (const float*)d_in[2];
    const float* Wn = (const float*)d_in[3];
    const float* bn = (const float*)d_in[4];
    const float* noise = (const float*)d_in[5];
    float* out_probs = (float*)d_out;
    float* out_idx = out_probs + (size_t)T_ * E_;

    const size_t WSP_BYTES = (size_t)2 * 32768 * 16;  // 1.0 MB
    if (ws_size >= WSP_BYTES) {
        h8* wsp = (h8*)d_ws;
        hipLaunchKernelGGL(w_split_kernel, dim3(128), dim3(256), 0, stream, Wg, Wn, wsp);
        hipLaunchKernelGGL(gemm_topk_kernel, dim3(T_ / BM), dim3(512), 0, stream,
                           x, wsp, bg, bn, noise, out_probs, out_idx);
    } else {
        hipLaunchKernelGGL(noisy_topk_f32_kernel, dim3(T_ / FBM), dim3(256), 0, stream,
                           x, Wg, bg, Wn, bn, noise, out_probs, out_idx);
    }
}

// Round 21
// 69.699 us; speedup vs baseline: 1.2068x; 1.2068x over previous
//
#include <hip/hip_runtime.h>
#include <math.h>
#include <stdint.h>

// NoisyTopKGating: B=4, S=4096, D=2048, E=64, K=2
#define D_ 2048
#define E_ 64
#define T_ 16384

#define BM 64                 // tokens per block
#define BK 64                 // k per tile (4 ks-steps of 16)
#define NT 32                 // D_/BK tiles
#define ABUF_B 16384          // A: 64 rows x 256 B f32 (XOR-swizzled 16B chunks)
#define BBUF_B 32768          // B: 2 planes x 4 frag x 4 ks x 1KB
#define BUF_B (ABUF_B + BBUF_B)   // 48 KB per buffer
#define CT_STRIDE 132         // fp32 C tile stride (epilogue)

typedef _Float16 h8 __attribute__((ext_vector_type(8)));    // 8 f16 (4 VGPR)
typedef float f16v __attribute__((ext_vector_type(16)));    // 32x32 MFMA acc

// in-register 2-plane f16 split: x = h + m/1024 (m scaled into normal range)
__device__ __forceinline__ void split2(const float4& a, const float4& b,
                                       h8& h, h8& m) {
    const float xe[8] = {a.x, a.y, a.z, a.w, b.x, b.y, b.z, b.w};
#pragma unroll
    for (int i = 0; i < 8; ++i) {
        const _Float16 hh_ = (_Float16)xe[i];              // v_cvt_f16_f32 (RNE)
        const float r = (xe[i] - (float)hh_) * 1024.0f;
        h[i] = hh_;
        m[i] = (_Float16)r;
    }
}

// async global->LDS DMA, 16 B per lane (dest = wave-uniform base + lane*16)
__device__ __forceinline__ void gload16(const void* g, void* l) {
    __builtin_amdgcn_global_load_lds(
        (const __attribute__((address_space(1))) uint32_t*)g,
        (__attribute__((address_space(3))) uint32_t*)l, 16, 0, 0);
}

// ================= per-token noisy top-2 epilogue (shared) ==================
__device__ __forceinline__ void topk_epilogue(float g, float nl, float nz,
                                              int lane, size_t tg,
                                              float* __restrict__ out_probs,
                                              float* __restrict__ out_idx) {
    // softplus(z) = max(z,0) + log1p(exp(-|z|))
    const float sp = fmaxf(nl, 0.f) + log1pf(expf(-fabsf(nl)));
    const float noisy = g + nz * sp;

    float v = noisy;
    int idx = lane;
#pragma unroll
    for (int off = 32; off > 0; off >>= 1) {
        const float ov = __shfl_xor(v, off);
        const int oi = __shfl_xor(idx, off);
        if (ov > v || (ov == v && oi < idx)) { v = ov; idx = oi; }
    }
    const float v1 = v;
    const int i1 = idx;
    v = (lane == i1) ? -INFINITY : noisy;
    idx = lane;
#pragma unroll
    for (int off = 32; off > 0; off >>= 1) {
        const float ov = __shfl_xor(v, off);
        const int oi = __shfl_xor(idx, off);
        if (ov > v || (ov == v && oi < idx)) { v = ov; idx = oi; }
    }
    const float v2 = v;
    const int i2 = idx;

    const float e2 = expf(v2 - v1);
    const float denom = 1.f + e2;
    const float p = (lane == i1) ? (1.f / denom)
                                 : ((lane == i2) ? (e2 / denom) : 0.f);
    out_probs[tg * E_ + lane] = p;
    if (lane == 0) {
        out_idx[tg * 2 + 0] = (float)i1;
        out_idx[tg * 2 + 1] = (float)i2;
    }
}

// ---------------- kernel 1: pre-split W into 2 f16 planes (32-col frags) ----
// Layout: plane p (mid x1024), frag f(4: 32 cols), ks-step s(128: 16 k),
// lane(64) -> h8.  n = f*32 + (lane&31), k = s*16 + (lane>>5)*8 + i.
__global__ void w_split_kernel(const float* __restrict__ Wg,
                               const float* __restrict__ Wn,
                               h8* __restrict__ wsp) {
    const int idx = blockIdx.x * blockDim.x + threadIdx.x;  // 0..32767
    const int lane = idx & 63;
    const int s = (idx >> 6) & 127;
    const int f = idx >> 13;
    const int n = f * 32 + (lane & 31);
    const int k0 = s * 16 + ((lane >> 5) << 3);
    const float* src = (n < 64) ? &Wg[(size_t)n * D_ + k0]
                                : &Wn[(size_t)(n - 64) * D_ + k0];
    h8 hv, mv;
#pragma unroll
    for (int i = 0; i < 8; ++i) {
        const float w = src[i];
        const _Float16 wh = (_Float16)w;
        const float r = (w - (float)wh) * 1024.0f;
        hv[i] = wh;
        mv[i] = (_Float16)r;
    }
    wsp[0 * 32768 + idx] = hv;
    wsp[1 * 32768 + idx] = mv;
}

// ---------------- kernel 2: 32x32x16 split-f16 MFMA GEMM + noisy top-2 -----
// BM=64, BK=64, grid=256 (1 block/CU). 512 threads = 8 waves = mh(2) x wn(4).
// ALL staging via global_load_lds DMA issued at phase start: A as raw f32
// (16B-chunk XOR swizzle, both sides - rule #21), B frag-linear. The barrier's
// vmcnt(0) then only waits on full-phase-old DMAs -> no exposed latency.
// Per-wave in-register split of its A rows. 1 barrier/tile, 96 KB LDS.
// 3 scaled products: logit = (ah*bh) + (ah*bm + am*bh)/2^10.
__launch_bounds__(512)
__global__ void gemm_topk_kernel(const float* __restrict__ x,
                                 const h8* __restrict__ wsp,
                                 const float* __restrict__ bg,
                                 const float* __restrict__ bn,
                                 const float* __restrict__ noise,
                                 float* __restrict__ out_probs,
                                 float* __restrict__ out_idx) {
    __shared__ __align__(16) char smem[2 * BUF_B];  // 98304 B
    const int tid = threadIdx.x;
    const int lane = tid & 63;
    const int wv = tid >> 6;           // 0..7
    const int mh = wv >> 2;            // 0..1: 32-row m-frag
    const int wn = wv & 3;             // 0..3: 32-col n-frag
    const int block_m0 = blockIdx.x * BM;
    const char* wb = (const char*)wsp;

    // ---- A staging: 1024 16B-chunks; thread covers cid_j = (wv*2+j)*64+lane.
    // row = cid>>4, c16 = lane&15; source chunk XOR-swizzled: c16 ^ (row&15).
    const int row0 = ((wv * 2 + 0) * 64 + lane) >> 4;
    const int row1 = ((wv * 2 + 1) * 64 + lane) >> 4;
    const int c16s = lane & 15;
    const float* asrc0 = x + (size_t)(block_m0 + row0) * D_ + ((c16s ^ (row0 & 15)) << 2);
    const float* asrc1 = x + (size_t)(block_m0 + row1) * D_ + ((c16s ^ (row1 & 15)) << 2);
    const int adst0 = ((wv * 2 + 0) * 64 + lane) * 16;
    const int adst1 = ((wv * 2 + 1) * 64 + lane) * 16;

    f16v hh = {}, cx = {};             // two scaled acc chains (32 VGPR)

    auto STAGE = [&](int t, int b) {
        char* Ab = smem + b * BUF_B;
        gload16(asrc0 + t * BK, Ab + adst0);
        gload16(asrc1 + t * BK, Ab + adst1);
        char* Bb = Ab + ABUF_B;
#pragma unroll
        for (int j = 0; j < 4; ++j) {
            const int rid = wv * 4 + j;   // p*16 + f*4 + ks
            const int p = rid >> 4, f = (rid & 15) >> 2, ks = rid & 3;
            gload16(wb + ((size_t)(p * 32768 + f * 8192 + (t * 4 + ks) * 64 + lane)) * 16,
                    Bb + rid * 1024 + lane * 16);
        }
    };

    // A read addressing: row = mh*32 + (lane&31); per ks two swizzled chunks
    const int arow = mh * 32 + (lane & 31);
    const int arsw = arow & 15;
    const int arbase = arow * 256;
    const int c16r = (lane >> 5) * 2;  // chunk pair base within ks

    auto COMPUTE = [&](int b) {
        const char* Ab = smem + b * BUF_B;
        const char* Bb = Ab + ABUF_B;
#pragma unroll
        for (int ks = 0; ks < 4; ++ks) {
            const int ca = ks * 4 + c16r;
            const float4 f0 = *(const float4*)(Ab + arbase + (((ca + 0) ^ arsw) << 4));
            const float4 f1 = *(const float4*)(Ab + arbase + (((ca + 1) ^ arsw) << 4));
            h8 ah, am;
            split2(f0, f1, ah, am);
            const h8 bh = *(const h8*)(Bb + (0 * 16 + wn * 4 + ks) * 1024 + lane * 16);
            const h8 bm = *(const h8*)(Bb + (1 * 16 + wn * 4 + ks) * 1024 + lane * 16);
            hh = __builtin_amdgcn_mfma_f32_32x32x16_f16(ah, bh, hh, 0, 0, 0);
            cx = __builtin_amdgcn_mfma_f32_32x32x16_f16(ah, bm, cx, 0, 0, 0);
            cx = __builtin_amdgcn_mfma_f32_32x32x16_f16(am, bh, cx, 0, 0, 0);
        }
    };

    // ---- main loop: DMA(t+1) at phase start || compute t; 1 barrier/tile ----
    STAGE(0, 0);
    __syncthreads();
    int cur = 0;
#pragma unroll 1
    for (int t = 0; t < NT; ++t) {
        if (t + 1 < NT) STAGE(t + 1, cur ^ 1);
        COMPUTE(cur);
        __syncthreads();
        cur ^= 1;
    }

    // ---- epilogue: combine scaled acc chains, C to LDS, noisy top-2 ----
    float* Ct = (float*)smem;  // [64][CT_STRIDE] = 33792 B
    {
        const float S1 = 1.0f / 1024.0f;
        const int col = wn * 32 + (lane & 31);
        const int rbase = 4 * (lane >> 5);
#pragma unroll
        for (int r = 0; r < 16; ++r) {
            const int row = mh * 32 + (r & 3) + 8 * (r >> 2) + rbase;
            Ct[row * CT_STRIDE + col] = hh[r] + cx[r] * S1;
        }
    }
    __syncthreads();

    const float my_bg = bg[lane];
    const float my_bn = bn[lane];
#pragma unroll 1
    for (int tt = 0; tt < 8; ++tt) {
        const int tl = wv * 8 + tt;
        const size_t tg = (size_t)block_m0 + tl;
        const float g = Ct[tl * CT_STRIDE + lane] + my_bg;
        const float nl = Ct[tl * CT_STRIDE + 64 + lane] + my_bn;
        const float nz = noise[tg * E_ + lane];
        topk_epilogue(g, nl, nz, lane, tg, out_probs, out_idx);
    }
}

// ---------------- fallback: pure-f32 fused kernel (no ws) -------------------
#define FBM 64
#define FBK 32
#define XS_STRIDE 68
#define WS_STRIDE 132
#define FCT_STRIDE 132

__launch_bounds__(256)
__global__ void noisy_topk_f32_kernel(const float* __restrict__ x,
                                      const float* __restrict__ Wg,
                                      const float* __restrict__ bg,
                                      const float* __restrict__ Wn,
                                      const float* __restrict__ bn,
                                      const float* __restrict__ noise,
                                      float* __restrict__ out_probs,
                                      float* __restrict__ out_idx) {
    __shared__ float smem[FBM * FCT_STRIDE];
    float* Xs = smem;
    float* Ws = smem + FBK * XS_STRIDE;

    const int tid = threadIdx.x;
    const int block_m0 = blockIdx.x * FBM;
    const int n0 = (tid & 31) * 4;
    const int m0 = (tid >> 5) * 8;

    float acc[8][4];
#pragma unroll
    for (int i = 0; i < 8; ++i)
#pragma unroll
        for (int j = 0; j < 4; ++j) acc[i][j] = 0.f;

    const int sj = tid & 7;
    const int sr = tid >> 3;

    for (int k0 = 0; k0 < D_; k0 += FBK) {
        __syncthreads();
#pragma unroll
        for (int it = 0; it < 2; ++it) {
            const int m = sr + it * 32;
            const float4 v = *reinterpret_cast<const float4*>(
                &x[(size_t)(block_m0 + m) * D_ + k0 + 4 * sj]);
            Xs[(4 * sj + 0) * XS_STRIDE + m] = v.x;
            Xs[(4 * sj + 1) * XS_STRIDE + m] = v.y;
            Xs[(4 * sj + 2) * XS_STRIDE + m] = v.z;
            Xs[(4 * sj + 3) * XS_STRIDE + m] = v.w;
        }
#pragma unroll
        for (int it = 0; it < 4; ++it) {
            const int n = sr + it * 32;
            const float* wrow = (n < 64) ? &Wg[(size_t)n * D_] : &Wn[(size_t)(n - 64) * D_];
            const float4 v = *reinterpret_cast<const float4*>(&wrow[k0 + 4 * sj]);
            Ws[(4 * sj + 0) * WS_STRIDE + n] = v.x;
            Ws[(4 * sj + 1) * WS_STRIDE + n] = v.y;
            Ws[(4 * sj + 2) * WS_STRIDE + n] = v.z;
            Ws[(4 * sj + 3) * WS_STRIDE + n] = v.w;
        }
        __syncthreads();
#pragma unroll
        for (int k = 0; k < FBK; ++k) {
            const float4 a0 = *reinterpret_cast<const float4*>(&Xs[k * XS_STRIDE + m0]);
            const float4 a1 = *reinterpret_cast<const float4*>(&Xs[k * XS_STRIDE + m0 + 4]);
            const float4 b4 = *reinterpret_cast<const float4*>(&Ws[k * WS_STRIDE + n0]);
            const float am[8] = {a0.x, a0.y, a0.z, a0.w, a1.x, a1.y, a1.z, a1.w};
            const float bb[4] = {b4.x, b4.y, b4.z, b4.w};
#pragma unroll
            for (int i = 0; i < 8; ++i)
#pragma unroll
                for (int j = 0; j < 4; ++j)
                    acc[i][j] = fmaf(am[i], bb[j], acc[i][j]);
        }
    }

    __syncthreads();
    float* Ct = smem;
#pragma unroll
    for (int i = 0; i < 8; ++i)
#pragma unroll
        for (int j = 0; j < 4; ++j)
            Ct[(m0 + i) * FCT_STRIDE + n0 + j] = acc[i][j];
    __syncthreads();

    const int wave = tid >> 6;
    const int lane = tid & 63;
    const float my_bg = bg[lane];
    const float my_bn = bn[lane];
#pragma unroll 1
    for (int tt = 0; tt < 16; ++tt) {
        const int tl = wave * 16 + tt;
        const size_t tg = (size_t)block_m0 + tl;
        const float g = Ct[tl * FCT_STRIDE + lane] + my_bg;
        const float nl = Ct[tl * FCT_STRIDE + 64 + lane] + my_bn;
        const float nz = noise[tg * E_ + lane];
        topk_epilogue(g, nl, nz, lane, tg, out_probs, out_idx);
    }
}

extern "C" void kernel_launch(void* const* d_in, const int* in_sizes, int n_in,
                              void* d_out, int out_size, void* d_ws, size_t ws_size,
                              hipStream_t stream) {
    const float* x = (const float*)d_in[0];
    const float* Wg = (const float*)d_in[1];
    const float* bg = (const float*)d_in[2];
    const float* Wn = (const float*)d_in[3];
    const float* bn = (const float*)d_in[4];
    const float* noise = (const float*)d_in[5];
    float* out_probs = (float*)d_out;
    float* out_idx = out_probs + (size_t)T_ * E_;

    const size_t WSP_BYTES = (size_t)2 * 32768 * 16;  // 1.0 MB
    if (ws_size >= WSP_BYTES) {
        h8* wsp = (h8*)d_ws;
        hipLaunchKernelGGL(w_split_kernel, dim3(128), dim3(256), 0, stream, Wg, Wn, wsp);
        hipLaunchKernelGGL(gemm_topk_kernel, dim3(T_ / BM), dim3(512), 0, stream,
                           x, wsp, bg, bn, noise, out_probs, out_idx);
    } else {
        hipLaunchKernelGGL(noisy_topk_f32_kernel, dim3(T_ / FBM), dim3(256), 0, stream,
                           x, Wg, bg, Wn, bn, noise, out_probs, out_idx);
    }
}

// Round 22
// 58.998 us; speedup vs baseline: 1.4257x; 1.1814x over previous
//
#include <hip/hip_runtime.h>
#include <math.h>
#include <stdint.h>

// NoisyTopKGating: B=4, S=4096, D=2048, E=64, K=2
#define D_ 2048
#define E_ 64
#define T_ 16384

#define BM 64                 // tokens per block
#define BK 64                 // k per tile (4 ks-steps of 16)
#define NT 32                 // D_/BK tiles
#define ABUF_B 16384          // A: 2 planes x 2 mf x 4 ks x 1KB (f16 frag-linear)
#define BBUF_B 32768          // B: 2 planes x 4 frag x 4 ks x 1KB
#define BUF_B (ABUF_B + BBUF_B)   // 48 KB per buffer
#define CT_STRIDE 132         // fp32 C tile stride (epilogue)

typedef _Float16 h8 __attribute__((ext_vector_type(8)));    // 8 f16 (4 VGPR)
typedef float f16v __attribute__((ext_vector_type(16)));    // 32x32 MFMA acc

// in-register 2-plane f16 split: x = h + m/1024 (m scaled into normal range)
__device__ __forceinline__ void split2(const float4& a, const float4& b,
                                       h8& h, h8& m) {
    const float xe[8] = {a.x, a.y, a.z, a.w, b.x, b.y, b.z, b.w};
#pragma unroll
    for (int i = 0; i < 8; ++i) {
        const _Float16 hh_ = (_Float16)xe[i];              // v_cvt_f16_f32 (RNE)
        const float r = (xe[i] - (float)hh_) * 1024.0f;
        h[i] = hh_;
        m[i] = (_Float16)r;
    }
}

// async global->LDS DMA, 16 B per lane (dest = wave-uniform base + lane*16)
__device__ __forceinline__ void gload16(const void* g, void* l) {
    __builtin_amdgcn_global_load_lds(
        (const __attribute__((address_space(1))) uint32_t*)g,
        (__attribute__((address_space(3))) uint32_t*)l, 16, 0, 0);
}

// ================= per-token noisy top-2 epilogue (shared) ==================
__device__ __forceinline__ void topk_epilogue(float g, float nl, float nz,
                                              int lane, size_t tg,
                                              float* __restrict__ out_probs,
                                              float* __restrict__ out_idx) {
    // softplus(z) = max(z,0) + log1p(exp(-|z|))
    const float sp = fmaxf(nl, 0.f) + log1pf(expf(-fabsf(nl)));
    const float noisy = g + nz * sp;

    float v = noisy;
    int idx = lane;
#pragma unroll
    for (int off = 32; off > 0; off >>= 1) {
        const float ov = __shfl_xor(v, off);
        const int oi = __shfl_xor(idx, off);
        if (ov > v || (ov == v && oi < idx)) { v = ov; idx = oi; }
    }
    const float v1 = v;
    const int i1 = idx;
    v = (lane == i1) ? -INFINITY : noisy;
    idx = lane;
#pragma unroll
    for (int off = 32; off > 0; off >>= 1) {
        const float ov = __shfl_xor(v, off);
        const int oi = __shfl_xor(idx, off);
        if (ov > v || (ov == v && oi < idx)) { v = ov; idx = oi; }
    }
    const float v2 = v;
    const int i2 = idx;

    const float e2 = expf(v2 - v1);
    const float denom = 1.f + e2;
    const float p = (lane == i1) ? (1.f / denom)
                                 : ((lane == i2) ? (e2 / denom) : 0.f);
    out_probs[tg * E_ + lane] = p;
    if (lane == 0) {
        out_idx[tg * 2 + 0] = (float)i1;
        out_idx[tg * 2 + 1] = (float)i2;
    }
}

// ---------------- kernel 1: pre-split W into 2 f16 planes (32-col frags) ----
// Layout: plane p (mid x1024), frag f(4: 32 cols), ks-step s(128: 16 k),
// lane(64) -> h8.  n = f*32 + (lane&31), k = s*16 + (lane>>5)*8 + i.
__global__ void w_split_kernel(const float* __restrict__ Wg,
                               const float* __restrict__ Wn,
                               h8* __restrict__ wsp) {
    const int idx = blockIdx.x * blockDim.x + threadIdx.x;  // 0..32767
    const int lane = idx & 63;
    const int s = (idx >> 6) & 127;
    const int f = idx >> 13;
    const int n = f * 32 + (lane & 31);
    const int k0 = s * 16 + ((lane >> 5) << 3);
    const float* src = (n < 64) ? &Wg[(size_t)n * D_ + k0]
                                : &Wn[(size_t)(n - 64) * D_ + k0];
    h8 hv, mv;
#pragma unroll
    for (int i = 0; i < 8; ++i) {
        const float w = src[i];
        const _Float16 wh = (_Float16)w;
        const float r = (w - (float)wh) * 1024.0f;
        hv[i] = wh;
        mv[i] = (_Float16)r;
    }
    wsp[0 * 32768 + idx] = hv;
    wsp[1 * 32768 + idx] = mv;
}

// ---------------- kernel 2: 32x32x16 split-f16 MFMA GEMM + noisy top-2 -----
// BM=64, BK=64, grid=256. 512 threads = 8 waves = mh(2) x wn(4); each wave
// computes one full 32x32 output frag over all k. A reg-staged (plain loads,
// split ONCE by staging threads into f16 frag-linear planes); B DMA'd via
// global_load_lds. 96 KB double-buffered LDS, 1 barrier/tile.
// 3 scaled products: logit = (ah*bh) + (ah*bm + am*bh)/2^10.
__launch_bounds__(512)
__global__ void gemm_topk_kernel(const float* __restrict__ x,
                                 const h8* __restrict__ wsp,
                                 const float* __restrict__ bg,
                                 const float* __restrict__ bn,
                                 const float* __restrict__ noise,
                                 float* __restrict__ out_probs,
                                 float* __restrict__ out_idx) {
    __shared__ __align__(16) char smem[2 * BUF_B];  // 98304 B
    const int tid = threadIdx.x;
    const int lane = tid & 63;
    const int wv = tid >> 6;           // 0..7
    const int mh = wv >> 2;            // 0..1: 32-row m-frag
    const int wn = wv & 3;             // 0..3: 32-col n-frag
    const int block_m0 = blockIdx.x * BM;
    const char* wb = (const char*)wsp;

    // A staging ownership: thread -> (smf, sks, sl); 2 x 4 x 64 = 512 threads.
    // A-frag semantics (32x32x16): row = sl&31, k = sks*16 + (sl>>5)*8 + i.
    const int smf = tid >> 8;          // m-frag 0..1 (32 rows each)
    const int sks = (tid >> 6) & 3;    // ks-step 0..3
    const int sl = tid & 63;
    const int srow = smf * 32 + (sl & 31);
    const float* asrc = x + (size_t)(block_m0 + srow) * D_
                          + sks * 16 + ((sl >> 5) << 3);
    const int aw_hi = (0 * 8 + smf * 4 + sks) * 1024 + sl * 16;
    const int aw_mid = (1 * 8 + smf * 4 + sks) * 1024 + sl * 16;

    f16v hh = {}, cx = {};             // two scaled acc chains (32 VGPR)

    // B staging: 32 rows of 1KB; rid = p*16 + f*4 + ks; 4 per wave
    auto STAGE_B = [&](int t, int b) {
        char* Bb = smem + b * BUF_B + ABUF_B;
#pragma unroll
        for (int j = 0; j < 4; ++j) {
            const int rid = wv * 4 + j;
            const int p = rid >> 4, f = (rid & 15) >> 2, ks = rid & 3;
            gload16(wb + ((size_t)(p * 32768 + f * 8192 + (t * 4 + ks) * 64 + lane)) * 16,
                    Bb + rid * 1024 + lane * 16);
        }
    };
    auto ALOAD = [&](int t, float4& ra, float4& rb) {
        ra = *(const float4*)(asrc + t * BK);
        rb = *(const float4*)(asrc + t * BK + 4);
    };
    auto ASPLIT = [&](const float4& ra, const float4& rb, int b) {
        h8 hv, mv;
        split2(ra, rb, hv, mv);
        char* Ab = smem + b * BUF_B;
        *(h8*)(Ab + aw_hi) = hv;
        *(h8*)(Ab + aw_mid) = mv;
    };
    auto COMPUTE = [&](int b) {
        const char* Ab = smem + b * BUF_B;
        const char* Bb = Ab + ABUF_B;
#pragma unroll
        for (int ks = 0; ks < 4; ++ks) {
            const h8 ah = *(const h8*)(Ab + (0 * 8 + mh * 4 + ks) * 1024 + lane * 16);
            const h8 am = *(const h8*)(Ab + (1 * 8 + mh * 4 + ks) * 1024 + lane * 16);
            const h8 bh = *(const h8*)(Bb + (0 * 16 + wn * 4 + ks) * 1024 + lane * 16);
            const h8 bm = *(const h8*)(Bb + (1 * 16 + wn * 4 + ks) * 1024 + lane * 16);
            hh = __builtin_amdgcn_mfma_f32_32x32x16_f16(ah, bh, hh, 0, 0, 0);
            cx = __builtin_amdgcn_mfma_f32_32x32x16_f16(ah, bm, cx, 0, 0, 0);
            cx = __builtin_amdgcn_mfma_f32_32x32x16_f16(am, bh, cx, 0, 0, 0);
        }
    };

    // ---- prologue ----
    float4 ra0, rb0, ra1, rb1;
    ALOAD(0, ra0, rb0);
    STAGE_B(0, 0);
    ASPLIT(ra0, rb0, 0);      // buf0 <- A(0)
    ALOAD(1, ra0, rb0);       // regs <- x(1)
    __syncthreads();

    // ---- main loop: 2 tiles per iteration (static register sets) ----
#pragma unroll 1
    for (int i = 0; i < NT / 2; ++i) {
        const int t = 2 * i;
        // tile t (buf0)
        STAGE_B(t + 1, 1);
        if (t + 2 < NT) ALOAD(t + 2, ra1, rb1);
        COMPUTE(0);
        ASPLIT(ra0, rb0, 1);
        __syncthreads();
        // tile t+1 (buf1)
        if (t + 2 < NT) STAGE_B(t + 2, 0);
        if (t + 3 < NT) ALOAD(t + 3, ra0, rb0);
        COMPUTE(1);
        if (t + 2 < NT) ASPLIT(ra1, rb1, 0);
        __syncthreads();
    }

    // ---- epilogue: combine scaled acc chains, C to LDS, noisy top-2 ----
    float* Ct = (float*)smem;  // [64][CT_STRIDE] = 33792 B
    {
        const float S1 = 1.0f / 1024.0f;
        const int col = wn * 32 + (lane & 31);
        const int rbase = 4 * (lane >> 5);
#pragma unroll
        for (int r = 0; r < 16; ++r) {
            const int row = mh * 32 + (r & 3) + 8 * (r >> 2) + rbase;
            Ct[row * CT_STRIDE + col] = hh[r] + cx[r] * S1;
        }
    }
    __syncthreads();

    const float my_bg = bg[lane];
    const float my_bn = bn[lane];
#pragma unroll 1
    for (int tt = 0; tt < 8; ++tt) {
        const int tl = wv * 8 + tt;
        const size_t tg = (size_t)block_m0 + tl;
        const float g = Ct[tl * CT_STRIDE + lane] + my_bg;
        const float nl = Ct[tl * CT_STRIDE + 64 + lane] + my_bn;
        const float nz = noise[tg * E_ + lane];
        topk_epilogue(g, nl, nz, lane, tg, out_probs, out_idx);
    }
}

// ---------------- fallback: pure-f32 fused kernel (no ws) -------------------
#define FBM 64
#define FBK 32
#define XS_STRIDE 68
#define WS_STRIDE 132
#define FCT_STRIDE 132

__launch_bounds__(256)
__global__ void noisy_topk_f32_kernel(const float* __restrict__ x,
                                      const float* __restrict__ Wg,
                                      const float* __restrict__ bg,
                                      const float* __restrict__ Wn,
                                      const float* __restrict__ bn,
                                      const float* __restrict__ noise,
                                      float* __restrict__ out_probs,
                                      float* __restrict__ out_idx) {
    __shared__ float smem[FBM * FCT_STRIDE];
    float* Xs = smem;
    float* Ws = smem + FBK * XS_STRIDE;

    const int tid = threadIdx.x;
    const int block_m0 = blockIdx.x * FBM;
    const int n0 = (tid & 31) * 4;
    const int m0 = (tid >> 5) * 8;

    float acc[8][4];
#pragma unroll
    for (int i = 0; i < 8; ++i)
#pragma unroll
        for (int j = 0; j < 4; ++j) acc[i][j] = 0.f;

    const int sj = tid & 7;
    const int sr = tid >> 3;

    for (int k0 = 0; k0 < D_; k0 += FBK) {
        __syncthreads();
#pragma unroll
        for (int it = 0; it < 2; ++it) {
            const int m = sr + it * 32;
            const float4 v = *reinterpret_cast<const float4*>(
                &x[(size_t)(block_m0 + m) * D_ + k0 + 4 * sj]);
            Xs[(4 * sj + 0) * XS_STRIDE + m] = v.x;
            Xs[(4 * sj + 1) * XS_STRIDE + m] = v.y;
            Xs[(4 * sj + 2) * XS_STRIDE + m] = v.z;
            Xs[(4 * sj + 3) * XS_STRIDE + m] = v.w;
        }
#pragma unroll
        for (int it = 0; it < 4; ++it) {
            const int n = sr + it * 32;
            const float* wrow = (n < 64) ? &Wg[(size_t)n * D_] : &Wn[(size_t)(n - 64) * D_];
            const float4 v = *reinterpret_cast<const float4*>(&wrow[k0 + 4 * sj]);
            Ws[(4 * sj + 0) * WS_STRIDE + n] = v.x;
            Ws[(4 * sj + 1) * WS_STRIDE + n] = v.y;
            Ws[(4 * sj + 2) * WS_STRIDE + n] = v.z;
            Ws[(4 * sj + 3) * WS_STRIDE + n] = v.w;
        }
        __syncthreads();
#pragma unroll
        for (int k = 0; k < FBK; ++k) {
            const float4 a0 = *reinterpret_cast<const float4*>(&Xs[k * XS_STRIDE + m0]);
            const float4 a1 = *reinterpret_cast<const float4*>(&Xs[k * XS_STRIDE + m0 + 4]);
            const float4 b4 = *reinterpret_cast<const float4*>(&Ws[k * WS_STRIDE + n0]);
            const float am[8] = {a0.x, a0.y, a0.z, a0.w, a1.x, a1.y, a1.z, a1.w};
            const float bb[4] = {b4.x, b4.y, b4.z, b4.w};
#pragma unroll
            for (int i = 0; i < 8; ++i)
#pragma unroll
                for (int j = 0; j < 4; ++j)
                    acc[i][j] = fmaf(am[i], bb[j], acc[i][j]);
        }
    }

    __syncthreads();
    float* Ct = smem;
#pragma unroll
    for (int i = 0; i < 8; ++i)
#pragma unroll
        for (int j = 0; j < 4; ++j)
            Ct[(m0 + i) * FCT_STRIDE + n0 + j] = acc[i][j];
    __syncthreads();

    const int wave = tid >> 6;
    const int lane = tid & 63;
    const float my_bg = bg[lane];
    const float my_bn = bn[lane];
#pragma unroll 1
    for (int tt = 0; tt < 16; ++tt) {
        const int tl = wave * 16 + tt;
        const size_t tg = (size_t)block_m0 + tl;
        const float g = Ct[tl * FCT_STRIDE + lane] + my_bg;
        const float nl = Ct[tl * FCT_STRIDE + 64 + lane] + my_bn;
        const float nz = noise[tg * E_ + lane];
        topk_epilogue(g, nl, nz, lane, tg, out_probs, out_idx);
    }
}

extern "C" void kernel_launch(void* const* d_in, const int* in_sizes, int n_in,
                              void* d_out, int out_size, void* d_ws, size_t ws_size,
                              hipStream_t stream) {
    const float* x = (const float*)d_in[0];
    const float* Wg = (const float*)d_in[1];
    const float* bg = (const float*)d_in[2];
    const float* Wn = (const float*)d_in[3];
    const float* bn = (const float*)d_in[4];
    const float* noise = (const float*)d_in[5];
    float* out_probs = (float*)d_out;
    float* out_idx = out_probs + (size_t)T_ * E_;

    const size_t WSP_BYTES = (size_t)2 * 32768 * 16;  // 1.0 MB
    if (ws_size >= WSP_BYTES) {
        h8* wsp = (h8*)d_ws;
        hipLaunchKernelGGL(w_split_kernel, dim3(128), dim3(256), 0, stream, Wg, Wn, wsp);
        hipLaunchKernelGGL(gemm_topk_kernel, dim3(T_ / BM), dim3(512), 0, stream,
                           x, wsp, bg, bn, noise, out_probs, out_idx);
    } else {
        hipLaunchKernelGGL(noisy_topk_f32_kernel, dim3(T_ / FBM), dim3(256), 0, stream,
                           x, Wg, bg, Wn, bn, noise, out_probs, out_idx);
    }
}

// Round 24
// 58.523 us; speedup vs baseline: 1.4372x; 1.0081x over previous
//
#include <hip/hip_runtime.h>
#include <math.h>
#include <stdint.h>

// NoisyTopKGating: B=4, S=4096, D=2048, E=64, K=2
#define D_ 2048
#define E_ 64
#define T_ 16384

#define BM 64                 // tokens per block
#define BK 64                 // k per tile (4 ks-steps of 16)
#define NT 32                 // D_/BK tiles
#define ABUF_B 16384          // A: 2 planes x 2 mf x 4 ks x 1KB (f16 frag-linear)
#define BBUF_B 32768          // B: 2 planes x 4 frag x 4 ks x 1KB
#define BUF_B (ABUF_B + BBUF_B)   // 48 KB per buffer
#define NBUF 3                // triple buffer: B staged 2 tiles ahead
#define CT_STRIDE 132         // fp32 C tile stride (epilogue)

typedef _Float16 h8 __attribute__((ext_vector_type(8)));    // 8 f16 (4 VGPR)
typedef float f16v __attribute__((ext_vector_type(16)));    // 32x32 MFMA acc

// in-register 2-plane f16 split: x = h + m/1024 (m scaled into normal range)
__device__ __forceinline__ void split2(const float4& a, const float4& b,
                                       h8& h, h8& m) {
    const float xe[8] = {a.x, a.y, a.z, a.w, b.x, b.y, b.z, b.w};
#pragma unroll
    for (int i = 0; i < 8; ++i) {
        const _Float16 hh_ = (_Float16)xe[i];              // v_cvt_f16_f32 (RNE)
        const float r = (xe[i] - (float)hh_) * 1024.0f;
        h[i] = hh_;
        m[i] = (_Float16)r;
    }
}

// async global->LDS DMA, 16 B per lane (dest = wave-uniform base + lane*16)
__device__ __forceinline__ void gload16(const void* g, void* l) {
    __builtin_amdgcn_global_load_lds(
        (const __attribute__((address_space(1))) uint32_t*)g,
        (__attribute__((address_space(3))) uint32_t*)l, 16, 0, 0);
}

// ================= per-token noisy top-2 epilogue (shared) ==================
__device__ __forceinline__ void topk_epilogue(float g, float nl, float nz,
                                              int lane, size_t tg,
                                              float* __restrict__ out_probs,
                                              float* __restrict__ out_idx) {
    // softplus(z) = max(z,0) + log1p(exp(-|z|))
    const float sp = fmaxf(nl, 0.f) + log1pf(expf(-fabsf(nl)));
    const float noisy = g + nz * sp;

    float v = noisy;
    int idx = lane;
#pragma unroll
    for (int off = 32; off > 0; off >>= 1) {
        const float ov = __shfl_xor(v, off);
        const int oi = __shfl_xor(idx, off);
        if (ov > v || (ov == v && oi < idx)) { v = ov; idx = oi; }
    }
    const float v1 = v;
    const int i1 = idx;
    v = (lane == i1) ? -INFINITY : noisy;
    idx = lane;
#pragma unroll
    for (int off = 32; off > 0; off >>= 1) {
        const float ov = __shfl_xor(v, off);
        const int oi = __shfl_xor(idx, off);
        if (ov > v || (ov == v && oi < idx)) { v = ov; idx = oi; }
    }
    const float v2 = v;
    const int i2 = idx;

    const float e2 = expf(v2 - v1);
    const float denom = 1.f + e2;
    const float p = (lane == i1) ? (1.f / denom)
                                 : ((lane == i2) ? (e2 / denom) : 0.f);
    out_probs[tg * E_ + lane] = p;
    if (lane == 0) {
        out_idx[tg * 2 + 0] = (float)i1;
        out_idx[tg * 2 + 1] = (float)i2;
    }
}

// ---------------- kernel 1: pre-split W into 2 f16 planes (32-col frags) ----
// Layout: plane p (mid x1024), frag f(4: 32 cols), ks-step s(128: 16 k),
// lane(64) -> h8.  n = f*32 + (lane&31), k = s*16 + (lane>>5)*8 + i.
__global__ void w_split_kernel(const float* __restrict__ Wg,
                               const float* __restrict__ Wn,
                               h8* __restrict__ wsp) {
    const int idx = blockIdx.x * blockDim.x + threadIdx.x;  // 0..32767
    const int lane = idx & 63;
    const int s = (idx >> 6) & 127;
    const int f = idx >> 13;
    const int n = f * 32 + (lane & 31);
    const int k0 = s * 16 + ((lane >> 5) << 3);
    const float* src = (n < 64) ? &Wg[(size_t)n * D_ + k0]
                                : &Wn[(size_t)(n - 64) * D_ + k0];
    h8 hv, mv;
#pragma unroll
    for (int i = 0; i < 8; ++i) {
        const float w = src[i];
        const _Float16 wh = (_Float16)w;
        const float r = (w - (float)wh) * 1024.0f;
        hv[i] = wh;
        mv[i] = (_Float16)r;
    }
    wsp[0 * 32768 + idx] = hv;
    wsp[1 * 32768 + idx] = mv;
}

// ---------------- kernel 2: 32x32x16 split-f16 MFMA GEMM + noisy top-2 -----
// BM=64, BK=64, grid=256. 512 threads = 8 waves = mh(2) x wn(4).
// Triple-buffered LDS: B DMA'd 2 tiles ahead via global_load_lds; A reg-staged
// 1 tile ahead (plain loads -> split once -> ds_write, consume-then-reload).
// Raw s_barrier with COUNTED vmcnt(6) (T4): tile t+1's B-DMA completes, the
// newest stage's 4 DMA + 2 A-loads stay in flight across the barrier.
// vmcnt(0) only in the last two phases.
// 3 scaled products: logit = (ah*bh) + (ah*bm + am*bh)/2^10.
__launch_bounds__(512)
__global__ void gemm_topk_kernel(const float* __restrict__ x,
                                 const h8* __restrict__ wsp,
                                 const float* __restrict__ bg,
                                 const float* __restrict__ bn,
                                 const float* __restrict__ noise,
                                 float* __restrict__ out_probs,
                                 float* __restrict__ out_idx) {
    __shared__ __align__(16) char smem[NBUF * BUF_B];  // 147456 B
    const int tid = threadIdx.x;
    const int lane = tid & 63;
    const int wv = tid >> 6;           // 0..7
    const int mh = wv >> 2;            // 0..1: 32-row m-frag
    const int wn = wv & 3;             // 0..3: 32-col n-frag
    const int block_m0 = blockIdx.x * BM;
    const char* wb = (const char*)wsp;

    // A staging ownership: thread -> (smf, sks, sl); 2 x 4 x 64 = 512 threads.
    // A-frag semantics (32x32x16): row = sl&31, k = sks*16 + (sl>>5)*8 + i.
    const int smf = tid >> 8;          // m-frag 0..1 (32 rows each)
    const int sks = (tid >> 6) & 3;    // ks-step 0..3
    const int sl = tid & 63;
    const int srow = smf * 32 + (sl & 31);
    const float* asrc = x + (size_t)(block_m0 + srow) * D_
                          + sks * 16 + ((sl >> 5) << 3);
    const int aw_hi = (0 * 8 + smf * 4 + sks) * 1024 + sl * 16;
    const int aw_mid = (1 * 8 + smf * 4 + sks) * 1024 + sl * 16;

    f16v hh = {}, cx = {};             // two scaled acc chains (32 VGPR)

    // B staging: 32 rows of 1KB; rid = p*16 + f*4 + ks; 4 per wave (4 DMA/thread)
    auto STAGE_B = [&](int t, int b) {
        char* Bb = smem + b * BUF_B + ABUF_B;
#pragma unroll
        for (int j = 0; j < 4; ++j) {
            const int rid = wv * 4 + j;
            const int p = rid >> 4, f = (rid & 15) >> 2, ks = rid & 3;
            gload16(wb + ((size_t)(p * 32768 + f * 8192 + (t * 4 + ks) * 64 + lane)) * 16,
                    Bb + rid * 1024 + lane * 16);
        }
    };
    auto ALOAD = [&](int t, float4& ra, float4& rb) {
        ra = *(const float4*)(asrc + t * BK);
        rb = *(const float4*)(asrc + t * BK + 4);
    };
    auto ASPLIT = [&](const float4& ra, const float4& rb, int b) {
        h8 hv, mv;
        split2(ra, rb, hv, mv);
        char* Ab = smem + b * BUF_B;
        *(h8*)(Ab + aw_hi) = hv;
        *(h8*)(Ab + aw_mid) = mv;
    };
    auto COMPUTE = [&](int b) {
        const char* Ab = smem + b * BUF_B;
        const char* Bb = Ab + ABUF_B;
#pragma unroll
        for (int ks = 0; ks < 4; ++ks) {
            const h8 ah = *(const h8*)(Ab + (0 * 8 + mh * 4 + ks) * 1024 + lane * 16);
            const h8 am = *(const h8*)(Ab + (1 * 8 + mh * 4 + ks) * 1024 + lane * 16);
            const h8 bh = *(const h8*)(Bb + (0 * 16 + wn * 4 + ks) * 1024 + lane * 16);
            const h8 bm = *(const h8*)(Bb + (1 * 16 + wn * 4 + ks) * 1024 + lane * 16);
            hh = __builtin_amdgcn_mfma_f32_32x32x16_f16(ah, bh, hh, 0, 0, 0);
            cx = __builtin_amdgcn_mfma_f32_32x32x16_f16(ah, bm, cx, 0, 0, 0);
            cx = __builtin_amdgcn_mfma_f32_32x32x16_f16(am, bh, cx, 0, 0, 0);
        }
    };

    // ---- prologue: establish 2-deep B pipeline, 1-deep A ----
    float4 ra0, rb0, ra1, rb1;
    ALOAD(0, ra0, rb0);
    STAGE_B(0, 0);             // B(0) -> buf0   (oldest DMAs)
    ASPLIT(ra0, rb0, 0);       // A(0) -> buf0   (consumes ra0/rb0)
    STAGE_B(1, 1);             // B(1) -> buf1
    ALOAD(1, ra0, rb0);        // A(1) regs (set0)
    ALOAD(2, ra1, rb1);        // A(2) regs (set1)
    // outstanding: B0(4) B1(4) A1(2) A2(2) = 12; drain B0 -> vmcnt(8)
    asm volatile("s_waitcnt vmcnt(8) lgkmcnt(0)" ::: "memory");
    __builtin_amdgcn_s_barrier();
    __builtin_amdgcn_sched_barrier(0);

    // ---- main loop: 2 tiles/iter, counted vmcnt at each barrier ----
    // Phase t: STAGE_B(t+2) | COMPUTE(t) | ASPLIT(A(t+1)) | ALOAD(t+3) |
    //          vmcnt(6): B(t+1) done, newest stage rides through barrier.
#pragma unroll 1
    for (int i = 0; i < NT / 2; ++i) {
        const int t = 2 * i;
        {   // even phase: compute t from buf[t%3]; A(t+1) lives in set0
            if (t + 2 < NT) STAGE_B(t + 2, (t + 2) % NBUF);
            COMPUTE(t % NBUF);
            ASPLIT(ra0, rb0, (t + 1) % NBUF);          // consume set0: A(t+1)
            if (t + 3 < NT) ALOAD(t + 3, ra0, rb0);    // reload set0: A(t+3)
            if (t < NT - 2) asm volatile("s_waitcnt vmcnt(6) lgkmcnt(0)" ::: "memory");
            else            asm volatile("s_waitcnt vmcnt(0) lgkmcnt(0)" ::: "memory");
            __builtin_amdgcn_s_barrier();
            __builtin_amdgcn_sched_barrier(0);
        }
        {   // odd phase: compute t+1 from buf[(t+1)%3]; A(t+2) lives in set1
            const int u = t + 1;
            if (u + 2 < NT) STAGE_B(u + 2, (u + 2) % NBUF);
            COMPUTE(u % NBUF);
            if (u + 1 < NT) ASPLIT(ra1, rb1, (u + 1) % NBUF);  // consume set1
            if (u + 3 < NT) ALOAD(u + 3, ra1, rb1);            // reload set1
            if (u < NT - 2) asm volatile("s_waitcnt vmcnt(6) lgkmcnt(0)" ::: "memory");
            else            asm volatile("s_waitcnt vmcnt(0) lgkmcnt(0)" ::: "memory");
            __builtin_amdgcn_s_barrier();
            __builtin_amdgcn_sched_barrier(0);
        }
    }

    // ---- epilogue: combine scaled acc chains, C to LDS, noisy top-2 ----
    __syncthreads();
    float* Ct = (float*)smem;  // [64][CT_STRIDE] = 33792 B
    {
        const float S1 = 1.0f / 1024.0f;
        const int col = wn * 32 + (lane & 31);
        const int rbase = 4 * (lane >> 5);
#pragma unroll
        for (int r = 0; r < 16; ++r) {
            const int row = mh * 32 + (r & 3) + 8 * (r >> 2) + rbase;
            Ct[row * CT_STRIDE + col] = hh[r] + cx[r] * S1;
        }
    }
    __syncthreads();

    const float my_bg = bg[lane];
    const float my_bn = bn[lane];
#pragma unroll 1
    for (int tt = 0; tt < 8; ++tt) {
        const int tl = wv * 8 + tt;
        const size_t tg = (size_t)block_m0 + tl;
        const float g = Ct[tl * CT_STRIDE + lane] + my_bg;
        const float nl = Ct[tl * CT_STRIDE + 64 + lane] + my_bn;
        const float nz = noise[tg * E_ + lane];
        topk_epilogue(g, nl, nz, lane, tg, out_probs, out_idx);
    }
}

// ---------------- fallback: pure-f32 fused kernel (no ws) -------------------
#define FBM 64
#define FBK 32
#define XS_STRIDE 68
#define WS_STRIDE 132
#define FCT_STRIDE 132

__launch_bounds__(256)
__global__ void noisy_topk_f32_kernel(const float* __restrict__ x,
                                      const float* __restrict__ Wg,
                                      const float* __restrict__ bg,
                                      const float* __restrict__ Wn,
                                      const float* __restrict__ bn,
                                      const float* __restrict__ noise,
                                      float* __restrict__ out_probs,
                                      float* __restrict__ out_idx) {
    __shared__ float smem[FBM * FCT_STRIDE];
    float* Xs = smem;
    float* Ws = smem + FBK * XS_STRIDE;

    const int tid = threadIdx.x;
    const int block_m0 = blockIdx.x * FBM;
    const int n0 = (tid & 31) * 4;
    const int m0 = (tid >> 5) * 8;

    float acc[8][4];
#pragma unroll
    for (int i = 0; i < 8; ++i)
#pragma unroll
        for (int j = 0; j < 4; ++j) acc[i][j] = 0.f;

    const int sj = tid & 7;
    const int sr = tid >> 3;

    for (int k0 = 0; k0 < D_; k0 += FBK) {
        __syncthreads();
#pragma unroll
        for (int it = 0; it < 2; ++it) {
            const int m = sr + it * 32;
            const float4 v = *reinterpret_cast<const float4*>(
                &x[(size_t)(block_m0 + m) * D_ + k0 + 4 * sj]);
            Xs[(4 * sj + 0) * XS_STRIDE + m] = v.x;
            Xs[(4 * sj + 1) * XS_STRIDE + m] = v.y;
            Xs[(4 * sj + 2) * XS_STRIDE + m] = v.z;
            Xs[(4 * sj + 3) * XS_STRIDE + m] = v.w;
        }
#pragma unroll
        for (int it = 0; it < 4; ++it) {
            const int n = sr + it * 32;
            const float* wrow = (n < 64) ? &Wg[(size_t)n * D_] : &Wn[(size_t)(n - 64) * D_];
            const float4 v = *reinterpret_cast<const float4*>(&wrow[k0 + 4 * sj]);
            Ws[(4 * sj + 0) * WS_STRIDE + n] = v.x;
            Ws[(4 * sj + 1) * WS_STRIDE + n] = v.y;
            Ws[(4 * sj + 2) * WS_STRIDE + n] = v.z;
            Ws[(4 * sj + 3) * WS_STRIDE + n] = v.w;
        }
        __syncthreads();
#pragma unroll
        for (int k = 0; k < FBK; ++k) {
            const float4 a0 = *reinterpret_cast<const float4*>(&Xs[k * XS_STRIDE + m0]);
            const float4 a1 = *reinterpret_cast<const float4*>(&Xs[k * XS_STRIDE + m0 + 4]);
            const float4 b4 = *reinterpret_cast<const float4*>(&Ws[k * WS_STRIDE + n0]);
            const float am[8] = {a0.x, a0.y, a0.z, a0.w, a1.x, a1.y, a1.z, a1.w};
            const float bb[4] = {b4.x, b4.y, b4.z, b4.w};
#pragma unroll
            for (int i = 0; i < 8; ++i)
#pragma unroll
                for (int j = 0; j < 4; ++j)
                    acc[i][j] = fmaf(am[i], bb[j], acc[i][j]);
        }
    }

    __syncthreads();
    float* Ct = smem;
#pragma unroll
    for (int i = 0; i < 8; ++i)
#pragma unroll
        for (int j = 0; j < 4; ++j)
            Ct[(m0 + i) * FCT_STRIDE + n0 + j] = acc[i][j];
    __syncthreads();

    const int wave = tid >> 6;
    const int lane = tid & 63;
    const float my_bg = bg[lane];
    const float my_bn = bn[lane];
#pragma unroll 1
    for (int tt = 0; tt < 16; ++tt) {
        const int tl = wave * 16 + tt;
        const size_t tg = (size_t)block_m0 + tl;
        const float g = Ct[tl * FCT_STRIDE + lane] + my_bg;
        const float nl = Ct[tl * FCT_STRIDE + 64 + lane] + my_bn;
        const float nz = noise[tg * E_ + lane];
        topk_epilogue(g, nl, nz, lane, tg, out_probs, out_idx);
    }
}

extern "C" void kernel_launch(void* const* d_in, const int* in_sizes, int n_in,
                              void* d_out, int out_size, void* d_ws, size_t ws_size,
                              hipStream_t stream) {
    const float* x = (const float*)d_in[0];
    const float* Wg = (const float*)d_in[1];
    const float* bg = (const float*)d_in[2];
    const float* Wn = (const float*)d_in[3];
    const float* bn = (const float*)d_in[4];
    const float* noise = (const float*)d_in[5];
    float* out_probs = (float*)d_out;
    float* out_idx = out_probs + (size_t)T_ * E_;

    const size_t WSP_BYTES = (size_t)2 * 32768 * 16;  // 1.0 MB
    if (ws_size >= WSP_BYTES) {
        h8* wsp = (h8*)d_ws;
        hipLaunchKernelGGL(w_split_kernel, dim3(128), dim3(256), 0, stream, Wg, Wn, wsp);
        hipLaunchKernelGGL(gemm_topk_kernel, dim3(T_ / BM), dim3(512), 0, stream,
                           x, wsp, bg, bn, noise, out_probs, out_idx);
    } else {
        hipLaunchKernelGGL(noisy_topk_f32_kernel, dim3(T_ / FBM), dim3(256), 0, stream,
                           x, Wg, bg, Wn, bn, noise, out_probs, out_idx);
    }
}